// Round 1
// baseline (6204.137 us; speedup 1.0000x reference)
//
#include <hip/hip_runtime.h>

// StyleWSConv: b=8, cin=cout=512, H=W=64, k=3, pad=1
// out[b,co,hw] = g[b,co] * sum_{ci,kh,kw} weight[co,ci,kh,kw]*t[b,ci]*x[b,ci,h+kh-1,w+kw-1]
//                + bias[co] + noise[b,hw]*ns
// g[b,co] = scale*A[co]/sqrt(A[co]^2*sum_ci t[b,ci]^2*wsq[co,ci] + eps), A=scale/wmax[co]

#define EPSV   1e-8f
#define SCALEV 0.014731391274719738f  // 1/sqrt(512*9)

// ---------------- per-filter stats: wmax[co], wsq[co][ci] ----------------
__global__ __launch_bounds__(256) void wstats_kernel(
    const float* __restrict__ weight, float* __restrict__ wmax, float* __restrict__ wsq)
{
    const int co = blockIdx.x;
    const int t  = threadIdx.x;
    const float* wp = weight + (size_t)co * 4608;
    float m = 0.f;
    for (int ci = t; ci < 512; ci += 256) {
        float s = 0.f;
        #pragma unroll
        for (int k = 0; k < 9; ++k) {
            float v = wp[ci * 9 + k];
            s = fmaf(v, v, s);
            m = fmaxf(m, fabsf(v));
        }
        wsq[co * 512 + ci] = s;
    }
    __shared__ float red[256];
    red[t] = m;
    __syncthreads();
    for (int s = 128; s > 0; s >>= 1) {
        if (t < s) red[t] = fmaxf(red[t], red[t + s]);
        __syncthreads();
    }
    if (t == 0) wmax[co] = red[0];
}

// ---------------- style inf-norm: t[b][ci] = style/smax ----------------
__global__ __launch_bounds__(512) void style_kernel(
    const float* __restrict__ style, float* __restrict__ tbuf)
{
    const int b = blockIdx.x;
    const int t = threadIdx.x;  // 512 threads
    float v = style[b * 512 + t];
    __shared__ float red[512];
    red[t] = fabsf(v);
    __syncthreads();
    for (int s = 256; s > 0; s >>= 1) {
        if (t < s) red[t] = fmaxf(red[t], red[t + s]);
        __syncthreads();
    }
    tbuf[b * 512 + t] = v / red[0];
}

// ---------------- demod coefficient g[b][co] ----------------
__global__ __launch_bounds__(256) void gcoef_kernel(
    const float* __restrict__ wmax, const float* __restrict__ wsq,
    const float* __restrict__ tbuf, float* __restrict__ gbuf)
{
    const int b    = blockIdx.y;
    const int co   = blockIdx.x * 4 + (threadIdx.x >> 6);  // one wave per co
    const int lane = threadIdx.x & 63;
    float sum = 0.f;
    for (int ci = lane; ci < 512; ci += 64) {
        float tv = tbuf[b * 512 + ci];
        sum = fmaf(tv * tv, wsq[co * 512 + ci], sum);
    }
    #pragma unroll
    for (int off = 32; off > 0; off >>= 1) sum += __shfl_down(sum, off);
    if (lane == 0) {
        float A = SCALEV / wmax[co];
        gbuf[b * 512 + co] = SCALEV * A / sqrtf(fmaf(A * A, sum, EPSV));
    }
}

// ---------------- main conv ----------------
// grid: (4 spatial tiles 32x32, 32 co-blocks of 16, 8 batch). block 256.
// thread: tx=col-block(8) ty=row-block(8) tc=co-group(4); 4co x 4x4px accum.
__global__ __launch_bounds__(256) void conv_kernel(
    const float* __restrict__ x, const float* __restrict__ weight,
    const float* __restrict__ tbuf, const float* __restrict__ gbuf,
    const float* __restrict__ bias, const float* __restrict__ noise,
    const float* __restrict__ nstr, float* __restrict__ out)
{
    __shared__ float xs[4][34][36];   // CI=4 halo tiles, row stride 36
    __shared__ float wsl[16][4][12];  // 16co x 4ci x 9 (pad 12)

    const int tid = threadIdx.x;
    const int b   = blockIdx.z;
    const int co0 = blockIdx.y << 4;
    const int th  = (blockIdx.x >> 1) << 5;
    const int tw  = (blockIdx.x & 1) << 5;

    const int tx = tid & 7;
    const int ty = (tid >> 3) & 7;
    const int tc = tid >> 6;

    float acc[4][16];
    #pragma unroll
    for (int i = 0; i < 4; ++i)
        #pragma unroll
        for (int j = 0; j < 16; ++j) acc[i][j] = 0.f;

    for (int ci0 = 0; ci0 < 512; ci0 += 4) {
        // stage input tile (with t[b,ci] folded in, zero halo)
        for (int i = tid; i < 4 * 34 * 34; i += 256) {
            int ci  = i / 1156;
            int rem = i - ci * 1156;
            int r   = rem / 34;
            int c   = rem - r * 34;
            int gh  = th + r - 1;
            int gw  = tw + c - 1;
            float v = 0.f;
            if ((unsigned)gh < 64u && (unsigned)gw < 64u)
                v = x[(((size_t)((b << 9) + ci0 + ci)) << 12) + (gh << 6) + gw]
                    * tbuf[(b << 9) + ci0 + ci];
            xs[ci][r][c] = v;
        }
        // stage weights
        for (int i = tid; i < 16 * 4 * 9; i += 256) {
            int co  = i / 36;
            int rem = i - co * 36;
            int ci  = rem / 9;
            int k   = rem - ci * 9;
            wsl[co][ci][k] = weight[(size_t)(co0 + co) * 4608 + (ci0 + ci) * 9 + k];
        }
        __syncthreads();

        #pragma unroll
        for (int ci = 0; ci < 4; ++ci) {
            float xb[6][6];
            #pragma unroll
            for (int r = 0; r < 6; ++r) {
                const float* rp = &xs[ci][4 * ty + r][4 * tx];
                float4 v4 = *(const float4*)rp;
                float2 v2 = *(const float2*)(rp + 4);
                xb[r][0] = v4.x; xb[r][1] = v4.y; xb[r][2] = v4.z; xb[r][3] = v4.w;
                xb[r][4] = v2.x; xb[r][5] = v2.y;
            }
            #pragma unroll
            for (int co = 0; co < 4; ++co) {
                const float* wp = &wsl[tc * 4 + co][ci][0];
                float4 wa = *(const float4*)wp;
                float4 wb = *(const float4*)(wp + 4);
                float w9[9] = {wa.x, wa.y, wa.z, wa.w, wb.x, wb.y, wb.z, wb.w, wp[8]};
                #pragma unroll
                for (int kh = 0; kh < 3; ++kh)
                    #pragma unroll
                    for (int kw = 0; kw < 3; ++kw) {
                        float wv = w9[kh * 3 + kw];
                        #pragma unroll
                        for (int r = 0; r < 4; ++r)
                            #pragma unroll
                            for (int c = 0; c < 4; ++c)
                                acc[co][r * 4 + c] =
                                    fmaf(wv, xb[r + kh][c + kw], acc[co][r * 4 + c]);
                    }
            }
        }
        __syncthreads();
    }

    // epilogue: out = g*acc + bias + noise*ns
    const float ns = nstr[0];
    #pragma unroll
    for (int co = 0; co < 4; ++co) {
        int cog  = co0 + tc * 4 + co;
        float gg = gbuf[(b << 9) + cog];
        float bb = bias[cog];
        #pragma unroll
        for (int r = 0; r < 4; ++r) {
            int h = th + 4 * ty + r;
            int w = tw + 4 * tx;
            const float4 nz = *(const float4*)&noise[(b << 12) + (h << 6) + w];
            float4 o;
            o.x = fmaf(gg, acc[co][r * 4 + 0], fmaf(nz.x, ns, bb));
            o.y = fmaf(gg, acc[co][r * 4 + 1], fmaf(nz.y, ns, bb));
            o.z = fmaf(gg, acc[co][r * 4 + 2], fmaf(nz.z, ns, bb));
            o.w = fmaf(gg, acc[co][r * 4 + 3], fmaf(nz.w, ns, bb));
            *(float4*)&out[(((size_t)((b << 9) + cog)) << 12) + (h << 6) + w] = o;
        }
    }
}

extern "C" void kernel_launch(void* const* d_in, const int* in_sizes, int n_in,
                              void* d_out, int out_size, void* d_ws, size_t ws_size,
                              hipStream_t stream)
{
    const float* x      = (const float*)d_in[0];
    const float* style  = (const float*)d_in[1];
    const float* noise  = (const float*)d_in[2];
    const float* weight = (const float*)d_in[3];
    const float* bias   = (const float*)d_in[4];
    const float* nstr   = (const float*)d_in[5];
    float* out = (float*)d_out;
    float* ws  = (float*)d_ws;

    float* wmax = ws;           // 512
    float* tbuf = ws + 512;     // 8*512
    float* wsq  = ws + 4608;    // 512*512
    float* gbuf = ws + 266752;  // 8*512   (total ~1.06 MB of d_ws)

    hipLaunchKernelGGL(wstats_kernel, dim3(512), dim3(256), 0, stream, weight, wmax, wsq);
    hipLaunchKernelGGL(style_kernel, dim3(8), dim3(512), 0, stream, style, tbuf);
    hipLaunchKernelGGL(gcoef_kernel, dim3(128, 8), dim3(256), 0, stream, wmax, wsq, tbuf, gbuf);
    hipLaunchKernelGGL(conv_kernel, dim3(4, 32, 8), dim3(256), 0, stream,
                       x, weight, tbuf, gbuf, bias, noise, nstr, out);
}

// Round 2
// 316.684 us; speedup vs baseline: 19.5910x; 19.5910x over previous
//
#include <hip/hip_runtime.h>

// StyleWSConv as 9-position implicit GEMM, bf16 MFMA (16x16x32), fp32 accum.
// out[b,co,p] = g[b,co] * sum_{pos,ci} wt[co,pos,ci] * xt[b,ci,p+shift(pos)]
//               + bias[co] + noise[b,p]*ns
// wt = w/wmax[co] (bf16), xt = t[b,ci]*x (bf16, padded NHWC), g fp32.

#define EPSV   1e-8f
#define SCALEV 0.014731391274719738f  // 1/sqrt(512*9)

typedef __attribute__((ext_vector_type(8))) short short8;
typedef __attribute__((ext_vector_type(4))) float floatx4;

__device__ __forceinline__ void gload_lds16(const void* g, void* l) {
    __builtin_amdgcn_global_load_lds(
        (const __attribute__((address_space(1))) void*)g,
        (__attribute__((address_space(3))) void*)l, 16, 0, 0);
}

__device__ __forceinline__ unsigned short f2bf(float f) {
    unsigned u = __float_as_uint(f);
    unsigned r = (u + 0x7fffu + ((u >> 16) & 1u)) >> 16;
    return (unsigned short)r;
}

// ---------------- zero xbp (border padding needs zeros) ----------------
__global__ __launch_bounds__(256) void zero_ws(uint4* __restrict__ p, int n4) {
    uint4 z = {0u, 0u, 0u, 0u};
    int stride = gridDim.x * 256;
    for (int i = blockIdx.x * 256 + threadIdx.x; i < n4; i += stride) p[i] = z;
}

// ---------------- style inf-norm: t[b][ci] ----------------
__global__ __launch_bounds__(512) void prep_style(
    const float* __restrict__ style, float* __restrict__ tbuf)
{
    const int b = blockIdx.x, t = threadIdx.x;
    float v = style[b * 512 + t];
    __shared__ float red[512];
    red[t] = fabsf(v);
    __syncthreads();
    for (int s = 256; s > 0; s >>= 1) {
        if (t < s) red[t] = fmaxf(red[t], red[t + s]);
        __syncthreads();
    }
    tbuf[b * 512 + t] = v / red[0];
}

// ---------------- weights: wmax-normalize -> bf16 Aw[co][9][512]; wsqn ----------------
__global__ __launch_bounds__(256) void prep_w(
    const float* __restrict__ weight, float* __restrict__ wsqn,
    unsigned short* __restrict__ Aw)
{
    const int co = blockIdx.x, t = threadIdx.x;
    const float* wp = weight + (size_t)co * 4608;
    float m = 0.f;
    for (int i = t; i < 4608; i += 256) m = fmaxf(m, fabsf(wp[i]));
    __shared__ float red[256];
    red[t] = m;
    __syncthreads();
    for (int s = 128; s > 0; s >>= 1) {
        if (t < s) red[t] = fmaxf(red[t], red[t + s]);
        __syncthreads();
    }
    const float inv = 1.f / red[0];
    for (int ci = t; ci < 512; ci += 256) {
        float s = 0.f;
        #pragma unroll
        for (int k = 0; k < 9; ++k) {
            float v = wp[ci * 9 + k] * inv;
            s = fmaf(v, v, s);
            Aw[(size_t)(co * 9 + k) * 512 + ci] = f2bf(v);
        }
        wsqn[co * 512 + ci] = s;
    }
}

// ---------------- x -> padded NHWC bf16 with t folded: xbp[b][66][66][512] ----------------
__global__ __launch_bounds__(256) void prep_x(
    const float* __restrict__ x, const float* __restrict__ tbuf,
    unsigned short* __restrict__ xbp)
{
    const int cic = blockIdx.x;  // 16 chunks of 32 ci
    const int h   = blockIdx.y;  // 64
    const int b   = blockIdx.z;  // 8
    const int tid = threadIdx.x;
    __shared__ float tr[64][33];

    const int cl = tid >> 3;           // 0..31 ci-local
    const int w0 = (tid & 7) << 3;     // 0..56
    const int ci = cic * 32 + cl;
    const float tv = tbuf[b * 512 + ci];
    const float* xp = x + (((size_t)(b * 512 + ci)) << 12) + (h << 6) + w0;
    float4 u = *(const float4*)xp;
    float4 v = *(const float4*)(xp + 4);
    tr[w0 + 0][cl] = u.x * tv; tr[w0 + 1][cl] = u.y * tv;
    tr[w0 + 2][cl] = u.z * tv; tr[w0 + 3][cl] = u.w * tv;
    tr[w0 + 4][cl] = v.x * tv; tr[w0 + 5][cl] = v.y * tv;
    tr[w0 + 6][cl] = v.z * tv; tr[w0 + 7][cl] = v.w * tv;
    __syncthreads();

    const int w  = tid >> 2;           // 0..63
    const int c8 = (tid & 3) << 3;     // 0,8,16,24
    unsigned short o[8] __attribute__((aligned(16)));
    #pragma unroll
    for (int j = 0; j < 8; ++j) o[j] = f2bf(tr[w][c8 + j]);
    size_t dst = ((size_t)((b * 66 + h + 1) * 66) + (w + 1)) * 512 + cic * 32 + c8;
    *(uint4*)&xbp[dst] = *(const uint4*)o;
}

// ---------------- demod coefficient g[b][co] ----------------
__global__ __launch_bounds__(256) void gcoef(
    const float* __restrict__ wsqn, const float* __restrict__ tbuf,
    float* __restrict__ gbuf)
{
    const int b    = blockIdx.y;
    const int co   = blockIdx.x * 4 + (threadIdx.x >> 6);
    const int lane = threadIdx.x & 63;
    float sum = 0.f;
    for (int ci = lane; ci < 512; ci += 64) {
        float tv = tbuf[b * 512 + ci];
        sum = fmaf(tv * tv, wsqn[co * 512 + ci], sum);
    }
    #pragma unroll
    for (int off = 32; off > 0; off >>= 1) sum += __shfl_down(sum, off);
    if (lane == 0)
        gbuf[b * 512 + co] = SCALEV * SCALEV / sqrtf(fmaf(SCALEV * SCALEV, sum, EPSV));
}

// ---------------- main: implicit-GEMM conv, 128co x 128px tile ----------------
// grid (32 px-blocks [16h x 2w], 4 co-blocks, 8 b), 256 threads (4 waves 2x2).
// K-chunk = 64 ci (two 32-ci LDS half-buffers), 9 kernel positions reuse B-tile.
__global__ __launch_bounds__(256, 2) void conv_mfma(
    const unsigned short* __restrict__ xbp, const unsigned short* __restrict__ Aw,
    const float* __restrict__ gbuf, const float* __restrict__ bias,
    const float* __restrict__ noise, const float* __restrict__ nstr,
    float* __restrict__ out)
{
    __shared__ __align__(16) short sA[2][4096];   // 128co x 32ci per half
    __shared__ __align__(16) short sB[2][6656];   // 208px(6r x 34c, padded) x 32ci per half

    const int tid  = threadIdx.x;
    const int lane = tid & 63;
    const int wv   = tid >> 6;
    const int b    = blockIdx.z;
    const int co0  = blockIdx.y << 7;
    const int h0   = (blockIdx.x >> 1) << 2;   // output row start (== padded row start)
    const int w0   = (blockIdx.x & 1) << 5;

    const int n0  = lane & 15;
    const int kq  = lane >> 4;
    const int wco = (wv >> 1) << 6;
    const int wpx = (wv & 1) << 6;

    int prow[4], pcol[4], aoff[4];
    #pragma unroll
    for (int fj = 0; fj < 4; ++fj) {
        int p = wpx + fj * 16 + n0;
        prow[fj] = p >> 5;
        pcol[fj] = p & 31;
    }
    #pragma unroll
    for (int fi = 0; fi < 4; ++fi) aoff[fi] = (wco + fi * 16 + n0) * 32 + kq * 8;

    const int sl_px = lane >> 2;        // staging: lane -> pixel/co row
    const int sl_ci = (lane & 3) << 3;  // staging: lane -> ci offset (8 bf16 = 16B)

    floatx4 zz = {0.f, 0.f, 0.f, 0.f};
    floatx4 acc[4][4];
    #pragma unroll
    for (int i = 0; i < 4; ++i)
        #pragma unroll
        for (int j = 0; j < 4; ++j) acc[i][j] = zz;

    const unsigned short* xb = xbp + (size_t)b * 4356 * 512;

    for (int ci0 = 0; ci0 < 512; ci0 += 64) {
        __syncthreads();
        // stage B tile: 6 rows x 34 cols x 64 ci (two halves), 13 wave-instrs/half
        #pragma unroll
        for (int hf = 0; hf < 2; ++hf) {
            const unsigned short* src = xb + ci0 + hf * 32 + sl_ci;
            for (int j = wv; j < 13; j += 4) {
                int px = j * 16 + sl_px;
                if (px > 203) px = 203;
                int row = px / 34;
                int col = px - row * 34;
                gload_lds16(src + (((size_t)(h0 + row) * 66 + w0 + col) << 9),
                            &sB[hf][j * 512]);
            }
        }
        #pragma unroll 1
        for (int pos = 0; pos < 9; ++pos) {
            const int kh = pos / 3;
            const int kw = pos - kh * 3;
            if (pos) __syncthreads();
            // stage A tile for this position: 128co x 64ci
            #pragma unroll
            for (int hf = 0; hf < 2; ++hf) {
                for (int j = wv; j < 8; j += 4) {
                    int co = j * 16 + sl_px;
                    gload_lds16(Aw + (size_t)((co0 + co) * 9 + pos) * 512
                                   + ci0 + hf * 32 + sl_ci,
                                &sA[hf][j * 512]);
                }
            }
            __syncthreads();
            #pragma unroll
            for (int hf = 0; hf < 2; ++hf) {
                short8 af[4], bfr[4];
                #pragma unroll
                for (int fi = 0; fi < 4; ++fi)
                    af[fi] = *(const short8*)&sA[hf][aoff[fi]];
                #pragma unroll
                for (int fj = 0; fj < 4; ++fj)
                    bfr[fj] = *(const short8*)
                        &sB[hf][((prow[fj] + kh) * 34 + pcol[fj] + kw) * 32 + kq * 8];
                #pragma unroll
                for (int fi = 0; fi < 4; ++fi)
                    #pragma unroll
                    for (int fj = 0; fj < 4; ++fj)
                        acc[fi][fj] = __builtin_amdgcn_mfma_f32_16x16x32_bf16(
                            af[fi], bfr[fj], acc[fi][fj], 0, 0, 0);
            }
        }
    }

    // epilogue: out = g*acc + bias + noise*ns
    const float ns = nstr[0];
    float nz[4];
    int ph[4], pw[4];
    #pragma unroll
    for (int fj = 0; fj < 4; ++fj) {
        int p = wpx + fj * 16 + n0;
        ph[fj] = h0 + (p >> 5);
        pw[fj] = w0 + (p & 31);
        nz[fj] = noise[(b << 12) + (ph[fj] << 6) + pw[fj]] * ns;
    }
    #pragma unroll
    for (int fi = 0; fi < 4; ++fi) {
        #pragma unroll
        for (int i = 0; i < 4; ++i) {
            int co = co0 + wco + fi * 16 + kq * 4 + i;
            float gg = gbuf[(b << 9) + co];
            float bb = bias[co];
            #pragma unroll
            for (int fj = 0; fj < 4; ++fj) {
                out[(((size_t)((b << 9) + co)) << 12) + (ph[fj] << 6) + pw[fj]] =
                    fmaf(gg, acc[fi][fj][i], bb + nz[fj]);
            }
        }
    }
}

extern "C" void kernel_launch(void* const* d_in, const int* in_sizes, int n_in,
                              void* d_out, int out_size, void* d_ws, size_t ws_size,
                              hipStream_t stream)
{
    const float* x      = (const float*)d_in[0];
    const float* style  = (const float*)d_in[1];
    const float* noise  = (const float*)d_in[2];
    const float* weight = (const float*)d_in[3];
    const float* bias   = (const float*)d_in[4];
    const float* nstr   = (const float*)d_in[5];
    float* out = (float*)d_out;
    char* ws = (char*)d_ws;

    // workspace layout (bytes)
    float*          tbuf = (float*)(ws);                    // 16384
    float*          gbuf = (float*)(ws + 16384);            // 16384
    float*          wsqn = (float*)(ws + 32768);            // 1048576
    unsigned short* Aw   = (unsigned short*)(ws + 1081344); // 4718592
    unsigned short* xbp  = (unsigned short*)(ws + 5799936); // 35684352 -> total ~41.5 MB

    hipLaunchKernelGGL(zero_ws, dim3(2048), dim3(256), 0, stream,
                       (uint4*)xbp, 35684352 / 16);
    hipLaunchKernelGGL(prep_style, dim3(8), dim3(512), 0, stream, style, tbuf);
    hipLaunchKernelGGL(prep_w, dim3(512), dim3(256), 0, stream, weight, wsqn, Aw);
    hipLaunchKernelGGL(prep_x, dim3(16, 64, 8), dim3(256), 0, stream, x, tbuf, xbp);
    hipLaunchKernelGGL(gcoef, dim3(128, 8), dim3(256), 0, stream, wsqn, tbuf, gbuf);
    hipLaunchKernelGGL(conv_mfma, dim3(32, 4, 8), dim3(256), 0, stream,
                       xbp, Aw, gbuf, bias, noise, nstr, out);
}